// Round 8
// baseline (227.931 us; speedup 1.0000x reference)
//
#include <hip/hip_runtime.h>
#include <hip/hip_bf16.h>

typedef __attribute__((ext_vector_type(8)))  short bf16x8;
typedef __attribute__((ext_vector_type(4)))  float f32x4;
typedef __attribute__((ext_vector_type(16))) float f32x16;

__device__ __forceinline__ unsigned short f2bf(float f) {
    unsigned int u = __builtin_bit_cast(unsigned int, f);
    u += 0x7fffu + ((u >> 16) & 1u);   // round-to-nearest-even
    return (unsigned short)(u >> 16);
}

// Swizzled byte offset inside the [128 rows][256 B] bf16 B^T tile.
// 16B-unit XOR: unit' = unit ^ (row & 15).
__device__ __forceinline__ int swz(int r, int k /*bf16 col*/) {
    int unit = k >> 3;
    return r * 256 + (((unit ^ (r & 15)) << 4) | ((k & 7) << 1));
}

__global__ __launch_bounds__(256, 2)
void gemm_persist(const float* __restrict__ A,  // (32, 2048, 128)
                  const float* __restrict__ B,  // (32, 128, 2048)
                  float* __restrict__ C) {      // (32, 2048, 2048)
    // LDS: only the transposed B tile (128n x 128k bf16, swizzled) = 32 KB,
    // staged ONCE per block; the 16-tile mt-loop is barrier-free.
    __shared__ __align__(16) unsigned char lds[32768];

    // XCD-chunked mapping: XCD x gets bh in [x*4, x*4+4).
    const int bid = blockIdx.x;                // 0..511
    const int c   = bid >> 3;                  // 0..63
    const int bh  = (bid & 7) * 4 + (c >> 4);  // 0..31
    const int nt  = c & 15;                    // 0..15

    const float* Bg  = B + (size_t)bh * (128 * 2048) + nt * 128;
    const float* Ag0 = A + (size_t)bh * (2048 * 128);
    float*       Cg0 = C + (size_t)bh * (2048 * 2048) + nt * 128;

    const int t = threadIdx.x;

    // ---- stage B tile: 128(k) x 128(n) fp32, in-register 4x4 transpose
    //      -> bf16 LDS Bt[n][k], swizzled ----
#pragma unroll
    for (int s = 0; s < 4; ++s) {
        const int k0 = s * 32 + ((t >> 5) << 2);
        const int n0 = (t & 31) << 2;
        const float4 r0 = *(const float4*)(Bg + (size_t)(k0 + 0) * 2048 + n0);
        const float4 r1 = *(const float4*)(Bg + (size_t)(k0 + 1) * 2048 + n0);
        const float4 r2 = *(const float4*)(Bg + (size_t)(k0 + 2) * 2048 + n0);
        const float4 r3 = *(const float4*)(Bg + (size_t)(k0 + 3) * 2048 + n0);
        const float c0[4] = {r0.x, r0.y, r0.z, r0.w};
        const float c1[4] = {r1.x, r1.y, r1.z, r1.w};
        const float c2[4] = {r2.x, r2.y, r2.z, r2.w};
        const float c3[4] = {r3.x, r3.y, r3.z, r3.w};
#pragma unroll
        for (int j = 0; j < 4; ++j) {
            uint2 w;
            w.x = (unsigned int)f2bf(c0[j]) | ((unsigned int)f2bf(c1[j]) << 16);
            w.y = (unsigned int)f2bf(c2[j]) | ((unsigned int)f2bf(c3[j]) << 16);
            *(uint2*)(&lds[swz(n0 + j, k0)]) = w;
        }
    }

    __syncthreads();

    // ---- persistent mt-loop: wave w owns rows [w*32, w*32+32) of each tile.
    // 32x32x16 MFMA: acc[ni] reg r, lane (kh,ml) holds
    //   C[(r&3) + 8*(r>>2) + 4*kh][ni*32 + ml]   (verified by R5 pass)
    const int l  = t & 63;
    const int w  = t >> 6;
    const int wm = w * 32;
    const int ml = l & 31;          // m-lane / n-lane
    const int kh = l >> 5;          // k-half (0/1)

    f32x4  raw[8][2];               // prefetched fp32 A row: 8 ksteps x 8 floats
    bf16x8 abf[8];                  // converted bf16 A fragments per kstep

    // prefetch tile 0: lane's A row (wm+ml), k = ks*16 + kh*8 + 0..7
    {
        const float* p = Ag0 + (size_t)(wm + ml) * 128 + kh * 8;
#pragma unroll
        for (int ks = 0; ks < 8; ++ks) {
            raw[ks][0] = *(const f32x4*)(p + ks * 16);
            raw[ks][1] = *(const f32x4*)(p + ks * 16 + 4);
        }
    }

#pragma unroll 1
    for (int mt = 0; mt < 16; ++mt) {
        // convert prefetched raw -> bf16 fragments
#pragma unroll
        for (int ks = 0; ks < 8; ++ks) {
            bf16x8 v;
#pragma unroll
            for (int j = 0; j < 4; ++j) {
                v[j]     = (short)f2bf(raw[ks][0][j]);
                v[4 + j] = (short)f2bf(raw[ks][1][j]);
            }
            abf[ks] = v;
        }

        // issue next tile's A loads BEFORE this tile's stores
        if (mt < 15) {
            const float* p = Ag0 + (size_t)((mt + 1) * 128 + wm + ml) * 128 + kh * 8;
#pragma unroll
            for (int ks = 0; ks < 8; ++ks) {
                raw[ks][0] = *(const f32x4*)(p + ks * 16);
                raw[ks][1] = *(const f32x4*)(p + ks * 16 + 4);
            }
        }

        f32x16 acc[4] = {};
#pragma unroll
        for (int ks = 0; ks < 8; ++ks) {
            const int kb = ks * 16 + kh * 8;
#pragma unroll
            for (int ni = 0; ni < 4; ++ni) {
                const bf16x8 b = *(const bf16x8*)(&lds[swz(ni * 32 + ml, kb)]);
                acc[ni] = __builtin_amdgcn_mfma_f32_32x32x16_bf16(
                    abf[ks], b, acc[ni], 0, 0, 0);
            }
        }

        // ---- store C: reassemble FULL rows via unambiguous half-wave
        // exchange (__shfl across lane^32), then PLAIN cached scalar stores:
        // each inst = 64 lanes x 4B = contiguous 256B-aligned span of ONE
        // row = 2 fully-covered 128B lines -> no RFO, no amplification
        // (the harness fill kernel proves this store shape: 2.1GB written,
        // 29KB fetched, 6.6 TB/s). ----
        float* Ct = Cg0 + (size_t)(mt * 128 + wm) * 2048;
#pragma unroll
        for (int p = 0; p < 2; ++p) {        // pair (2p,2p+1): cols p*64 .. p*64+63
#pragma unroll
            for (int r = 0; r < 16; ++r) {
                const float x = acc[2 * p][r];      // rows m', m'+4 ; cols p*64+ml
                const float y = acc[2 * p + 1][r];  // rows m', m'+4 ; cols p*64+32+ml
                const float xs = __shfl(x, l ^ 32); // other half's x
                const float ys = __shfl(y, l ^ 32); // other half's y
                // rlo: full row m'  (lane l -> col p*64 + l)
                // rhi: full row m'+4
                const float rlo = (l < 32) ? x : ys;
                const float rhi = (l < 32) ? xs : y;
                const int m = (r & 3) + 8 * (r >> 2);
                Ct[(size_t)m * 2048       + p * 64 + l] = rlo;
                Ct[(size_t)(m + 4) * 2048 + p * 64 + l] = rhi;
            }
        }
    }
}

extern "C" void kernel_launch(void* const* d_in, const int* in_sizes, int n_in,
                              void* d_out, int out_size, void* d_ws, size_t ws_size,
                              hipStream_t stream) {
    const float* x1 = (const float*)d_in[0];  // (2,16,2048,128)
    const float* x2 = (const float*)d_in[1];  // (2,16,128,2048)
    float* out = (float*)d_out;               // (2,16,2048,2048)
    gemm_persist<<<dim3(512), dim3(256), 0, stream>>>(x1, x2, out);
}